// Round 1
// baseline (250.600 us; speedup 1.0000x reference)
//
#include <hip/hip_runtime.h>

// Problem constants (fixed by setup_inputs).
#define B_SZ 4
#define C_CH 12
#define H_G 16
#define W_G 16
#define D_G 8
#define H_IM 1024
#define W_IM 1024

// LDS layout: Q[c][h][d] as float2 pairs (P[d], P[min(d+1,7)]),
// h-row pitch padded 8 -> 9 float2 to spread LDS banks.
#define QPITCH 9
#define QCSTRIDE (H_G * QPITCH)   // float2 per channel = 144

__global__ __launch_bounds__(256) void bilateral_slice_kernel(
    const float* __restrict__ grid,
    const float* __restrict__ guide,
    float* __restrict__ out)
{
    __shared__ float2 Q[C_CH * QCSTRIDE];   // 12*144*8B = 13824 B

    const int blk = blockIdx.x;
    const int b = blk >> 10;      // blk / H_IM
    const int i = blk & 1023;     // blk % H_IM
    const int t = threadIdx.x;

    // Row-constant grid-W coordinate (reference: ww = i/(H-1) * (Wg-1)).
    const float wwv = ((float)i / 1023.0f) * 15.0f;
    const float w0f = floorf(wwv);
    const int   w0  = (int)w0f;
    const int   w1  = min(w0 + 1, W_G - 1);
    const float fw  = wwv - w0f;

    // ---- Precompute Q: lerp grid along Wg for this row, pack d-pairs ----
    if (t < C_CH * H_G) {
        const int c = t >> 4;     // t / 16
        const int h = t & 15;     // t % 16
        const float* gp = grid +
            ((((size_t)b * C_CH + c) * H_G + h) * W_G + w0) * D_G;
        const int w1off = (w1 - w0) * D_G;  // 8 or 0
        const float4 a0 = *(const float4*)(gp);
        const float4 a1 = *(const float4*)(gp + 4);
        const float4 b0 = *(const float4*)(gp + w1off);
        const float4 b1 = *(const float4*)(gp + w1off + 4);
        float pd[8];
        pd[0] = a0.x + fw * (b0.x - a0.x);
        pd[1] = a0.y + fw * (b0.y - a0.y);
        pd[2] = a0.z + fw * (b0.z - a0.z);
        pd[3] = a0.w + fw * (b0.w - a0.w);
        pd[4] = a1.x + fw * (b1.x - a1.x);
        pd[5] = a1.y + fw * (b1.y - a1.y);
        pd[6] = a1.z + fw * (b1.z - a1.z);
        pd[7] = a1.w + fw * (b1.w - a1.w);
        float2* qrow = &Q[(c * H_G + h) * QPITCH];
        #pragma unroll
        for (int d = 0; d < 8; ++d) {
            const int dn = (d < 7) ? (d + 1) : 7;
            qrow[d] = make_float2(pd[d], pd[dn]);
        }
    }
    __syncthreads();

    // ---- Main: 4 consecutive pixels per thread ----
    const int j0 = t << 2;
    const float4 g4 = *(const float4*)(guide + (((size_t)b * H_IM) + i) * W_IM + j0);

    int   off0[4], off1[4];
    float dwv[4], fhv[4];
    const float* gv = (const float*)&g4;
    #pragma unroll
    for (int p = 0; p < 4; ++p) {
        // depth coordinate (reference: clip(floor(g*7),0,7), clip(frac,0,1))
        const float dc  = gv[p] * 7.0f;
        float dlf = floorf(dc);
        dlf = fminf(fmaxf(dlf, 0.0f), 7.0f);
        const int dlo = (int)dlf;
        dwv[p] = fminf(fmaxf(dc - dlf, 0.0f), 1.0f);
        // grid-H coordinate from column j (reference: hh = j/(W-1) * (Hg-1))
        const int   j   = j0 + p;
        const float hhv = ((float)j / 1023.0f) * 15.0f;
        const float h0f = floorf(hhv);
        const int   h0  = (int)h0f;
        const int   h1  = min(h0 + 1, H_G - 1);
        fhv[p] = hhv - h0f;
        off0[p] = h0 * QPITCH + dlo;
        off1[p] = h1 * QPITCH + dlo;
    }

    float* outp = out + (((size_t)b * C_CH) * H_IM + i) * W_IM + j0;
    #pragma unroll
    for (int c = 0; c < C_CH; ++c) {
        const float2* Qc = &Q[c * QCSTRIDE];
        float4 o;
        float* ov = (float*)&o;
        #pragma unroll
        for (int p = 0; p < 4; ++p) {
            const float2 qa = Qc[off0[p]];
            const float2 qb = Qc[off1[p]];
            const float va = qa.x + dwv[p] * (qa.y - qa.x);  // lerp over d @ h0
            const float vb = qb.x + dwv[p] * (qb.y - qb.x);  // lerp over d @ h1
            ov[p] = va + fhv[p] * (vb - va);                 // lerp over h
        }
        *(float4*)(outp + (size_t)c * (H_IM * W_IM)) = o;
    }
}

extern "C" void kernel_launch(void* const* d_in, const int* in_sizes, int n_in,
                              void* d_out, int out_size, void* d_ws, size_t ws_size,
                              hipStream_t stream) {
    const float* grid  = (const float*)d_in[0];
    const float* guide = (const float*)d_in[1];
    // d_in[2] (input_image) is only used for its shape in the reference.
    float* out = (float*)d_out;

    const int nblocks = B_SZ * H_IM;   // one block per (b, row)
    bilateral_slice_kernel<<<nblocks, 256, 0, stream>>>(grid, guide, out);
}

// Round 3
// 247.723 us; speedup vs baseline: 1.0116x; 1.0116x over previous
//
#include <hip/hip_runtime.h>

// Problem constants (fixed by setup_inputs).
#define B_SZ 4
#define C_CH 12
#define H_G 16
#define W_G 16
#define D_G 8
#define H_IM 1024
#define W_IM 1024

// Quad-cell LDS layout: cell(h,d) holds, for each channel c, the float4
//   { P[h][d], P[h][dn], P[h1][d], P[h1][dn] }   (dn=min(d+1,7), h1=min(h+1,15))
// where P is the grid row already lerped along Wg for this image row.
// One ds_read_b128 + 4 FMA gives one pixel-channel output.
// Cell stride 13 float4 (208 B): bank-quad = (52*(8h+d)+4c) mod 32 spreads d
// over all 8 quad positions (52*d mod 32 = {0,20,8,28,16,4,24,12}).
#define CELL_F4 13
// LDS: 16*8 cells * 13 float4 * 16 B = 26624 B -> 6 blocks/CU (LDS-limited)

// Native clang vector for nontemporal stores (HIP float4 class is rejected).
typedef float vfloat4 __attribute__((ext_vector_type(4)));

__global__ __launch_bounds__(256) void bilateral_slice_kernel(
    const float* __restrict__ grid,
    const float* __restrict__ guide,
    float* __restrict__ out)
{
    __shared__ float4 Qs[H_G * D_G * CELL_F4];

    const int blk = blockIdx.x;
    const int b = blk >> 10;      // blk / H_IM
    const int i = blk & 1023;     // blk % H_IM
    const int t = threadIdx.x;

    // Row-constant grid-W coordinate (reference: ww = i/(H-1) * (Wg-1)).
    const float wwv = ((float)i / 1023.0f) * 15.0f;
    const float w0f = floorf(wwv);
    const int   w0  = (int)w0f;
    const int   w1  = min(w0 + 1, W_G - 1);
    const float fw  = wwv - w0f;

    // ---- Precompute quad-cells: thread t -> (channel c, grid-row h) ----
    if (t < C_CH * H_G) {
        const int c  = t >> 4;    // t / 16
        const int h  = t & 15;    // t % 16
        const int h1 = min(h + 1, H_G - 1);
        const float* r0 = grid + (((size_t)(b * C_CH + c) * H_G + h ) * W_G) * D_G;
        const float* r1 = grid + (((size_t)(b * C_CH + c) * H_G + h1) * W_G) * D_G;
        const int o0 = w0 * D_G;
        const int o1 = w1 * D_G;
        float A[8], Bv[8], Cv[8], Dv[8];
        *(float4*)&A [0] = *(const float4*)(r0 + o0);
        *(float4*)&A [4] = *(const float4*)(r0 + o0 + 4);
        *(float4*)&Bv[0] = *(const float4*)(r0 + o1);
        *(float4*)&Bv[4] = *(const float4*)(r0 + o1 + 4);
        *(float4*)&Cv[0] = *(const float4*)(r1 + o0);
        *(float4*)&Cv[4] = *(const float4*)(r1 + o0 + 4);
        *(float4*)&Dv[0] = *(const float4*)(r1 + o1);
        *(float4*)&Dv[4] = *(const float4*)(r1 + o1 + 4);
        float P[8], P1[8];
        #pragma unroll
        for (int d = 0; d < 8; ++d) {
            P [d] = A [d] + fw * (Bv[d] - A [d]);   // w-lerp @ h
            P1[d] = Cv[d] + fw * (Dv[d] - Cv[d]);   // w-lerp @ h1
        }
        float4* cell = &Qs[(h * D_G) * CELL_F4 + c];
        #pragma unroll
        for (int d = 0; d < 8; ++d) {
            const int dn = (d < 7) ? d + 1 : 7;
            cell[d * CELL_F4] = make_float4(P[d], P[dn], P1[d], P1[dn]);
        }
    }
    __syncthreads();

    // ---- Main: 4 consecutive pixels per thread, all 12 channels ----
    const int j0 = t << 2;
    const float4 g4 = *(const float4*)(guide + ((size_t)b * H_IM + i) * W_IM + j0);
    const float* gv = (const float*)&g4;

    float o[C_CH][4];
    #pragma unroll
    for (int p = 0; p < 4; ++p) {
        // depth coordinate (reference: clip(floor(g*7),0,7), clip(frac,0,1))
        const float dc  = gv[p] * 7.0f;
        float dlf = floorf(dc);
        dlf = fminf(fmaxf(dlf, 0.0f), 7.0f);
        const int   dlo = (int)dlf;
        const float dw  = fminf(fmaxf(dc - dlf, 0.0f), 1.0f);
        // grid-H coordinate from column j (reference: hh = j/(W-1) * (Hg-1))
        const int   j   = j0 + p;
        const float hhv = ((float)j / 1023.0f) * 15.0f;
        const float h0f = floorf(hhv);
        const int   h0  = (int)h0f;
        const float fh  = hhv - h0f;

        const float wA = (1.0f - fh) * (1.0f - dw);
        const float wB = (1.0f - fh) * dw;
        const float wC = fh * (1.0f - dw);
        const float wD = fh * dw;

        const float4* cellp = &Qs[(h0 * D_G + dlo) * CELL_F4];
        #pragma unroll
        for (int c = 0; c < C_CH; ++c) {
            const float4 q = cellp[c];   // single base + offset-immediate reads
            o[c][p] = wA * q.x + wB * q.y + wC * q.z + wD * q.w;
        }
    }

    float* outp = out + (((size_t)b * C_CH) * H_IM + i) * W_IM + j0;
    #pragma unroll
    for (int c = 0; c < C_CH; ++c) {
        vfloat4 v = { o[c][0], o[c][1], o[c][2], o[c][3] };
        // write-once output: keep it out of L2
        __builtin_nontemporal_store(v, (vfloat4*)(outp + (size_t)c * (H_IM * W_IM)));
    }
}

extern "C" void kernel_launch(void* const* d_in, const int* in_sizes, int n_in,
                              void* d_out, int out_size, void* d_ws, size_t ws_size,
                              hipStream_t stream) {
    const float* grid  = (const float*)d_in[0];
    const float* guide = (const float*)d_in[1];
    // d_in[2] (input_image) is only used for its shape in the reference.
    float* out = (float*)d_out;

    const int nblocks = B_SZ * H_IM;   // one block per (b, row)
    bilateral_slice_kernel<<<nblocks, 256, 0, stream>>>(grid, guide, out);
}